// Round 4
// baseline (151.594 us; speedup 1.0000x reference)
//
#include <hip/hip_runtime.h>
#include <hip/hip_bf16.h>

#define NN 3072
#define RR 8
#define JP 4                 // j's per thread
#define TPR (NN / JP)        // 768 threads per row (64 | 768 -> i wave-uniform)

typedef float f4 __attribute__((ext_vector_type(4)));
typedef int   i4 __attribute__((ext_vector_type(4)));

__global__ __launch_bounds__(256) void frd_kernel(
    const float* __restrict__ z,       // [N, R]
    const int*   __restrict__ seg,     // [N, N]
    const int*   __restrict__ cls,     // [N]
    const int*   __restrict__ batch,   // [N]
    float*       __restrict__ out)     // [N, N, R]
{
    const int gid = blockIdx.x * 256 + threadIdx.x;
    const int i   = gid / TPR;                 // wave-uniform (64 | TPR)
    const int j0  = (gid - i * TPR) * JP;      // 16B-aligned along j

    // row-side (uniform -> scalar loads, broadcast)
    const int  ci = cls[i];
    const int  bi = batch[i];
    const bool im = (ci < 24);                 // labels in [0,27)
    const f4* zip = (const f4*)(z + (long long)i * RR);
    const f4 a0 = zip[0], a1 = zip[1];

    // column-side: vector loads, coalesced
    const i4 cj = *(const i4*)(cls + j0);
    const i4 bj = *(const i4*)(batch + j0);
    const i4 s  = *(const i4*)(seg + (long long)i * NN + j0);

    const f4 d0 = {1.0f, 0.0f, 0.0f, 0.0f};
    const f4 d1 = {0.0f, 0.0f, 0.0f, 0.0f};

    f4* o = (f4*)(out + ((long long)i * NN + j0) * RR);

#pragma unroll
    for (int k = 0; k < JP; ++k) {
        const int j = j0 + k;
        // seg_matrix in {0,1}; +eye -> diagonal never selected: (s==0 && i!=j)
        const bool pm = (s[k] == 0) & (i != j) & im & (cj[k] < 24) & (bi == bj[k]);

        const f4* zjp = (const f4*)(z + (long long)j * RR);
        const f4 b0 = zjp[0], b1 = zjp[1];

        o[2 * k]     = pm ? (a0 * b0) : d0;
        o[2 * k + 1] = pm ? (a1 * b1) : d1;
    }
}

extern "C" void kernel_launch(void* const* d_in, const int* in_sizes, int n_in,
                              void* d_out, int out_size, void* d_ws, size_t ws_size,
                              hipStream_t stream) {
    const float* z     = (const float*)d_in[0];
    const int*   seg   = (const int*)d_in[1];
    const int*   cls   = (const int*)d_in[2];
    const int*   batch = (const int*)d_in[3];
    float* out = (float*)d_out;

    const int total_threads = NN * TPR;        // 2,359,296
    const int grid = total_threads / 256;      // 9216 blocks
    frd_kernel<<<grid, dim3(256), 0, stream>>>(z, seg, cls, batch, out);
}

// Round 5
// 89.216 us; speedup vs baseline: 1.6992x; 1.6992x over previous
//
#include <hip/hip_runtime.h>
#include <hip/hip_bf16.h>

#define NN 3072
#define RR 8

typedef float f4 __attribute__((ext_vector_type(4)));

// Two threads per (i,j) pair; thread h in {0,1} owns one float4 of the
// 8-float output. Wave stores are perfectly contiguous: lane l writes
// bytes [16l, 16l+16) of a 1 KiB block (same pattern as the 7 TB/s fill).
__global__ __launch_bounds__(256) void frd_kernel(
    const float* __restrict__ z,       // [N, R]
    const int*   __restrict__ seg,     // [N, N]
    const int*   __restrict__ cls,     // [N]
    const int*   __restrict__ batch,   // [N]
    float*       __restrict__ out)     // [N, N, R]
{
    const int gid = blockIdx.x * 256 + threadIdx.x;  // < NN*NN*2 (fits int)
    const int h = gid & 1;                           // which half of the pair
    const int p = gid >> 1;                          // pair index
    const int i = p / NN;                            // wave-uniform (32 pairs/wave, 3072%32==0)
    const int j = p - i * NN;

    // mask inputs (seg line shared by lane pairs; cls/batch/z L2-resident)
    const int s  = seg[p];
    const int ci = cls[i];
    const int bi = batch[i];
    const int cj = cls[j];
    const int bj = batch[j];

    // seg_matrix in {0,1}; +eye -> diagonal never selected: (s==0 && i!=j).
    // labels in [0,27): "not in {24,25,26}" <=> (< 24).
    const bool pm = (s == 0) & (i != j) & (ci < 24) & (cj < 24) & (bi == bj);

    const f4 a = *(const f4*)(z + i * RR + h * 4);
    const f4 b = *(const f4*)(z + j * RR + h * 4);

    f4 dflt;
    dflt.x = h ? 0.0f : 1.0f;
    dflt.y = 0.0f; dflt.z = 0.0f; dflt.w = 0.0f;

    const f4 r = pm ? (a * b) : dflt;

    *(f4*)(out + (long long)gid * 4) = r;            // contiguous 16B/lane
}

extern "C" void kernel_launch(void* const* d_in, const int* in_sizes, int n_in,
                              void* d_out, int out_size, void* d_ws, size_t ws_size,
                              hipStream_t stream) {
    const float* z     = (const float*)d_in[0];
    const int*   seg   = (const int*)d_in[1];
    const int*   cls   = (const int*)d_in[2];
    const int*   batch = (const int*)d_in[3];
    float* out = (float*)d_out;

    const long long total_threads = (long long)NN * NN * 2;  // 18,874,368
    const int grid = (int)(total_threads / 256);              // 73,728 blocks
    frd_kernel<<<grid, dim3(256), 0, stream>>>(z, seg, cls, batch, out);
}

// Round 6
// 71.228 us; speedup vs baseline: 2.1283x; 1.2525x over previous
//
#include <hip/hip_runtime.h>
#include <hip/hip_bf16.h>

#define NN 3072
#define RR 8
#define JP 4                 // pairs per scatter-thread
#define TPR (NN / JP)        // 768

typedef float f4 __attribute__((ext_vector_type(4)));
typedef int   i4 __attribute__((ext_vector_type(4)));

// Pass 1: pure fill of the default pattern [1,0,0,0,0,0,0,0] per pair.
// Identical addressing to the 7 TB/s rocclr fill: lane l stores bytes
// [16l,16l+16) of a contiguous 1 KiB block.
__global__ __launch_bounds__(256) void fill_default(f4* __restrict__ out)
{
    const int t = blockIdx.x * 256 + threadIdx.x;   // < 18,874,368
    f4 v;
    v.x = (t & 1) ? 0.0f : 1.0f;
    v.y = 0.0f; v.z = 0.0f; v.w = 0.0f;
    out[t] = v;
}

// Pass 2: read seg as a pure 16B/lane stream; scatter z[i]*z[j] into the
// ~2.4% of pairs that are selected.
__global__ __launch_bounds__(256) void scatter_pairs(
    const float* __restrict__ z,       // [N, R]
    const int*   __restrict__ seg,     // [N, N]
    const int*   __restrict__ cls,     // [N]
    const int*   __restrict__ batch,   // [N]
    float*       __restrict__ out)     // [N, N, R]
{
    const int gid = blockIdx.x * 256 + threadIdx.x;  // < NN*TPR
    const int i   = gid / TPR;                       // wave-uniform
    const int j0  = (gid - i * TPR) * JP;

    const int  ci = cls[i];
    const int  bi = batch[i];
    // labels in [0,27): "not in {24,25,26}" <=> (< 24)
    if (ci >= 24) return;                            // whole row default

    const i4 s  = *(const i4*)(seg + (long long)i * NN + j0);
    const i4 cj = *(const i4*)(cls + j0);
    const i4 bj = *(const i4*)(batch + j0);

    // seg_matrix in {0,1}; +eye -> diagonal never selected: (s==0 && i!=j)
    bool any = false;
    bool pm[JP];
#pragma unroll
    for (int k = 0; k < JP; ++k) {
        pm[k] = (s[k] == 0) & (i != j0 + k) & (cj[k] < 24) & (bi == bj[k]);
        any |= pm[k];
    }
    if (!any) return;

    const f4* zip = (const f4*)(z + (long long)i * RR);
    const f4 a0 = zip[0], a1 = zip[1];

#pragma unroll
    for (int k = 0; k < JP; ++k) {
        if (pm[k]) {
            const int j = j0 + k;
            const f4* zjp = (const f4*)(z + (long long)j * RR);
            const f4 b0 = zjp[0], b1 = zjp[1];
            f4* o = (f4*)(out + ((long long)i * NN + j) * RR);
            o[0] = a0 * b0;
            o[1] = a1 * b1;
        }
    }
}

extern "C" void kernel_launch(void* const* d_in, const int* in_sizes, int n_in,
                              void* d_out, int out_size, void* d_ws, size_t ws_size,
                              hipStream_t stream) {
    const float* z     = (const float*)d_in[0];
    const int*   seg   = (const int*)d_in[1];
    const int*   cls   = (const int*)d_in[2];
    const int*   batch = (const int*)d_in[3];
    float* out = (float*)d_out;

    // Pass 1: 18,874,368 f4 stores -> 73,728 blocks
    const int fill_threads = NN * NN * 2;
    fill_default<<<fill_threads / 256, 256, 0, stream>>>((f4*)out);

    // Pass 2: 2,359,296 threads -> 9,216 blocks
    const int scat_threads = NN * TPR;
    scatter_pairs<<<scat_threads / 256, 256, 0, stream>>>(z, seg, cls, batch, out);
}

// Round 7
// 60.684 us; speedup vs baseline: 2.4981x; 1.1738x over previous
//
#include <hip/hip_runtime.h>
#include <hip/hip_bf16.h>

#define NN 3072
#define RR 8

typedef float f4 __attribute__((ext_vector_type(4)));

// Pass 1: pure fill of the default pattern [1,0,0,0,0,0,0,0] per pair.
// Same addressing as the 7 TB/s rocclr fill: lane l stores 16 contiguous
// bytes; a wave covers a contiguous 1 KiB block.
__global__ __launch_bounds__(256) void fill_default(f4* __restrict__ out)
{
    const int t = blockIdx.x * 256 + threadIdx.x;   // < 18,874,368
    f4 v;
    v.x = (t & 1) ? 0.0f : 1.0f;
    v.y = 0.0f; v.z = 0.0f; v.w = 0.0f;
    out[t] = v;
}

// Pass 2: batch is sorted -> same-batch pairs are contiguous diagonal
// blocks (~6% of the matrix). One wave per row: binary-search the row's
// block [lo,hi), scan only those columns, scatter z[i]*z[j] where selected.
__global__ __launch_bounds__(256) void scatter_pairs(
    const float* __restrict__ z,       // [N, R]
    const int*   __restrict__ seg,     // [N, N]
    const int*   __restrict__ cls,     // [N]
    const int*   __restrict__ batch,   // [N]
    float*       __restrict__ out)     // [N, N, R]
{
    const int i    = (blockIdx.x * 256 + threadIdx.x) >> 6;  // one wave per row
    const int lane = threadIdx.x & 63;

    // labels in [0,27): "not in {24,25,26}" <=> (< 24)
    const int ci = cls[i];
    if (ci >= 24) return;                  // whole row stays default
    const int bi = batch[i];

    // [lo,hi) = columns with batch[j] == bi (uniform binary search, L2-hot)
    int l = 0, r = NN;
    while (l < r) { const int m = (l + r) >> 1; if (batch[m] <  bi) l = m + 1; else r = m; }
    const int lo = l;
    r = NN;
    while (l < r) { const int m = (l + r) >> 1; if (batch[m] <= bi) l = m + 1; else r = m; }
    const int hi = l;

    const f4* zip = (const f4*)(z + (long long)i * RR);
    const f4 a0 = zip[0], a1 = zip[1];
    const long long rowbase = (long long)i * NN;

    for (int j = lo + lane; j < hi; j += 64) {
        // seg_matrix in {0,1}; +eye -> diagonal never selected: (s==0 && i!=j)
        const int s = seg[rowbase + j];
        const bool pm = (s == 0) & (i != j) & (cls[j] < 24);
        if (pm) {
            const f4* zjp = (const f4*)(z + (long long)j * RR);
            f4* o = (f4*)(out + (rowbase + j) * RR);
            o[0] = a0 * zjp[0];
            o[1] = a1 * zjp[1];
        }
    }
}

extern "C" void kernel_launch(void* const* d_in, const int* in_sizes, int n_in,
                              void* d_out, int out_size, void* d_ws, size_t ws_size,
                              hipStream_t stream) {
    const float* z     = (const float*)d_in[0];
    const int*   seg   = (const int*)d_in[1];
    const int*   cls   = (const int*)d_in[2];
    const int*   batch = (const int*)d_in[3];
    float* out = (float*)d_out;

    // Pass 1: 18,874,368 f4 stores -> 73,728 blocks
    fill_default<<<(NN * NN * 2) / 256, 256, 0, stream>>>((f4*)out);

    // Pass 2: one wave per row -> 3072 waves -> 768 blocks
    scatter_pairs<<<(NN * 64) / 256, 256, 0, stream>>>(z, seg, cls, batch, out);
}